// Round 12
// baseline (738.967 us; speedup 1.0000x reference)
//
#include <hip/hip_runtime.h>
#include <hip/hip_bf16.h>

// BinaryLinear: out = x @ sign(W)^T
// x: [32,4096,1024] f32 -> A [M=131072][K=1024]
// W: [1024,1024] f32    -> B^T = sign(W) [N=1024][K=1024] bf16 in d_ws (once)
// out: [M][N] f32
//
// R12 = R11 with ONE change: __launch_bounds__(256) -- NO min-waves arg.
// Diagnosed pattern: any min-waves value (R8/R9/R11) makes the compiler pick
// VGPR=64 and serialize the 8x float4 A-staging into exposed round-trips
// (MfmaUtil 15%). Plain (256) lets it keep the staging in flight (R2: 116).
// Also: B gll issued BEFORE the A reg-loads (queue drains B first).
// Structure (R6-verbatim race-free 2-barrier step), bf16-A XOR layout
// (0 conflicts measured in R11), B path, epilogue, XCD swizzle: unchanged.

typedef __attribute__((ext_vector_type(8))) short bf16x8;
typedef __attribute__((ext_vector_type(4))) float f32x4;

#define BM 128
#define BN 128
#define BK 64
#define KDIM 1024
#define NDIM 1024
#define NKSTEP (KDIM / BK)

__device__ __forceinline__ unsigned cvt2(float a, float b) {
  unsigned r;
  asm("v_cvt_pk_bf16_f32 %0, %1, %2" : "=v"(r) : "v"(a), "v"(b));
  return r;
}

// ---- pre-kernel: Bs[n][k] = sign(W[n][k]) as bf16 (+1, -1, or 0) ----
__global__ void sign_kernel(const float4* __restrict__ W, ushort4* __restrict__ Bs, int n4) {
  int i = blockIdx.x * blockDim.x + threadIdx.x;
  if (i >= n4) return;
  float4 v = W[i];
  const float* pv = (const float*)&v;
  ushort4 r;
  unsigned short* pr = (unsigned short*)&r;
#pragma unroll
  for (int j = 0; j < 4; ++j) {
    union { float f; unsigned int u; } c; c.f = pv[j];
    pr[j] = ((c.u & 0x7fffffffu) == 0u)
                ? (unsigned short)0
                : (unsigned short)(0x3f80u | ((c.u >> 16) & 0x8000u));
  }
  Bs[i] = r;
}

// ---- main GEMM ----
__global__ __launch_bounds__(256) void bgemm_kernel(
    const float* __restrict__ X,
    const unsigned short* __restrict__ Bs,
    float* __restrict__ O) {
  // A: 128 rows x 64 bf16, linear 128B rows, chunk c at slot c^(row&7) -> 16 KB
  // B: 128 rows x 64 bf16, chunk-XOR slot (R6 verbatim)                -> 16 KB
  __shared__ unsigned short sA[BM * BK];
  __shared__ unsigned short sB[BN * BK];

  const int t = threadIdx.x;
  const int l = t & 63;
  const int w = t >> 6;
  const int wr = w >> 1;  // 2x2 wave grid, wave tile 64x64
  const int wc = w & 1;

  // XCD-bijective swizzle; bn fastest => 8 N-sharers of an M-tile on one XCD.
  const unsigned nwg = gridDim.x;
  unsigned swz = blockIdx.x;
  if ((nwg & 7u) == 0u) swz = (blockIdx.x & 7u) * (nwg >> 3) + (blockIdx.x >> 3);
  const int bm = (int)(swz >> 3);
  const int bn = (int)(swz & 7u);
  const size_t m0 = (size_t)bm * BM;
  const int N0 = bn * BN;

  // A staging: thread owns row ar = t>>1, half h = t&1 -> 32 contiguous f32
  // (128B/lane global). Stores 4 bf16-chunks at XOR'd slots.
  const int ar = t >> 1;
  const int ah = t & 1;
  const float* agl = X + (m0 + (size_t)ar) * KDIM + ah * 32;
  int awo[4];  // ushort offsets of the 4 chunk writes
#pragma unroll
  for (int c = 0; c < 4; ++c)
    awo[c] = ar * BK + (((ah * 4 + c) ^ (ar & 7)) * 8);

  // B staging: 128x64 bf16 = 1024 16B-chunks, 4 gll/thread (R6 verbatim).
  // LDS chunk c = n*8 + s holds global k-octet q = s ^ (n&7).
  const unsigned short* bgp[4];
  int bw[4];
#pragma unroll
  for (int i = 0; i < 4; ++i) {
    int c = i * 256 + t;
    int n = c >> 3;
    int q = (c & 7) ^ (n & 7);
    bgp[i] = Bs + (size_t)(N0 + n) * KDIM + q * 8;
    bw[i] = c * 8;  // linear dest (gll rule)
  }

  // fragment read offsets (2 k-subs of 32 per BK=64 step)
  const int ll = l & 15;
  const int kb = l >> 4;
  int offA[2][4];
  int offB[2][4];
#pragma unroll
  for (int ks = 0; ks < 2; ++ks) {
#pragma unroll
    for (int i = 0; i < 4; ++i) {
      int row = wr * 64 + i * 16 + ll;
      offA[ks][i] = row * BK + (((ks * 4 + kb) ^ (row & 7)) * 8);
    }
#pragma unroll
    for (int j = 0; j < 4; ++j) {
      int n = wc * 64 + j * 16 + ll;
      offB[ks][j] = n * BK + (((ks * 4 + kb) ^ (n & 7)) * 8);
    }
  }

  f32x4 acc[4][4];
#pragma unroll
  for (int i = 0; i < 4; ++i)
#pragma unroll
    for (int j = 0; j < 4; ++j) acc[i][j] = (f32x4)0.0f;

  for (int kk = 0; kk < NKSTEP; ++kk) {
    const int k0 = kk * BK;

    // ---- stage phase ----
    // B -> LDS via gll FIRST (front of the vmcnt queue)
#pragma unroll
    for (int i = 0; i < 4; ++i)
      __builtin_amdgcn_global_load_lds(
          (const __attribute__((address_space(1))) void*)(bgp[i] + k0),
          (__attribute__((address_space(3))) void*)(&sB[bw[i]]), 16, 0, 0);
    // A f32 -> regs (8x float4, 128B/lane coalesced) -- kept in flight
    const float4* ap = reinterpret_cast<const float4*>(agl + k0);
    float4 f0 = ap[0], f1 = ap[1], f2 = ap[2], f3 = ap[3];
    float4 f4 = ap[4], f5 = ap[5], f6 = ap[6], f7 = ap[7];
    // cvt + XOR-slot ds_write_b128 x4
    uint4 q0, q1, q2, q3;
    q0.x = cvt2(f0.x, f0.y); q0.y = cvt2(f0.z, f0.w);
    q0.z = cvt2(f1.x, f1.y); q0.w = cvt2(f1.z, f1.w);
    q1.x = cvt2(f2.x, f2.y); q1.y = cvt2(f2.z, f2.w);
    q1.z = cvt2(f3.x, f3.y); q1.w = cvt2(f3.z, f3.w);
    q2.x = cvt2(f4.x, f4.y); q2.y = cvt2(f4.z, f4.w);
    q2.z = cvt2(f5.x, f5.y); q2.w = cvt2(f5.z, f5.w);
    q3.x = cvt2(f6.x, f6.y); q3.y = cvt2(f6.z, f6.w);
    q3.z = cvt2(f7.x, f7.y); q3.w = cvt2(f7.z, f7.w);
    *reinterpret_cast<uint4*>(&sA[awo[0]]) = q0;
    *reinterpret_cast<uint4*>(&sA[awo[1]]) = q1;
    *reinterpret_cast<uint4*>(&sA[awo[2]]) = q2;
    *reinterpret_cast<uint4*>(&sA[awo[3]]) = q3;
    // drain: B gll landed + A ds_writes visible before anyone crosses
    asm volatile("s_waitcnt vmcnt(0) lgkmcnt(0)" ::: "memory");
    __syncthreads();

    // ---- compute: 2 k-subs x 16 MFMA ----
#pragma unroll
    for (int ks = 0; ks < 2; ++ks) {
      bf16x8 av[4];
      bf16x8 bv[4];
#pragma unroll
      for (int i = 0; i < 4; ++i)
        av[i] = *reinterpret_cast<const bf16x8*>(sA + offA[ks][i]);
#pragma unroll
      for (int j = 0; j < 4; ++j)
        bv[j] = *reinterpret_cast<const bf16x8*>(sB + offB[ks][j]);
#pragma unroll
      for (int i = 0; i < 4; ++i)
#pragma unroll
        for (int j = 0; j < 4; ++j)
          acc[i][j] = __builtin_amdgcn_mfma_f32_16x16x32_bf16(
              av[i], bv[j], acc[i][j], 0, 0, 0);
    }
    __syncthreads();  // all reads done before next step's stage overwrites
  }

  // epilogue: C/D layout col = lane&15, row = (lane>>4)*4 + reg
  const int crow = kb * 4;
#pragma unroll
  for (int i = 0; i < 4; ++i) {
    const size_t r0 = m0 + wr * 64 + i * 16 + crow;
#pragma unroll
    for (int j = 0; j < 4; ++j) {
      const int col = N0 + wc * 64 + j * 16 + ll;
      float* op = O + r0 * NDIM + col;
#pragma unroll
      for (int e = 0; e < 4; ++e) op[(size_t)e * NDIM] = acc[i][j][e];
    }
  }
}

// ---- fallback (only if ws too small for the 2 MiB sign buffer) ----
__global__ void naive_kernel(const float* __restrict__ X, const float* __restrict__ W,
                             float* __restrict__ O, long long total) {
  long long idx = (long long)blockIdx.x * blockDim.x + threadIdx.x;
  if (idx >= total) return;
  int n = (int)(idx & (NDIM - 1));
  long long m = idx >> 10;
  const float* xr = X + m * KDIM;
  const float* wr = W + (long long)n * KDIM;
  float s = 0.f;
  for (int k = 0; k < KDIM; ++k) {
    float wv = wr[k];
    float sg = (wv > 0.f) ? 1.f : ((wv < 0.f) ? -1.f : 0.f);
    s += xr[k] * sg;
  }
  O[idx] = s;
}

extern "C" void kernel_launch(void* const* d_in, const int* in_sizes, int n_in,
                              void* d_out, int out_size, void* d_ws, size_t ws_size,
                              hipStream_t stream) {
  const float* X = (const float*)d_in[0];
  const float* W = (const float*)d_in[1];
  float* O = (float*)d_out;
  const long long M = (long long)in_sizes[0] / KDIM;  // 131072

  const size_t need_ws = (size_t)NDIM * KDIM * sizeof(unsigned short);  // 2 MiB
  if (ws_size >= need_ws && (M % BM) == 0) {
    unsigned short* Bs = (unsigned short*)d_ws;
    int n4 = (NDIM * KDIM) / 4;
    sign_kernel<<<dim3(n4 / 256), dim3(256), 0, stream>>>(
        (const float4*)W, (ushort4*)Bs, n4);
    dim3 grid((unsigned)((M / BM) * (NDIM / BN)));  // 8192
    bgemm_kernel<<<grid, dim3(256), 0, stream>>>(X, Bs, O);
  } else {
    long long total = M * NDIM;
    long long blocks = (total + 255) / 256;
    naive_kernel<<<dim3((unsigned)blocks), dim3(256), 0, stream>>>(X, W, O, total);
  }
}

// Round 13
// 662.888 us; speedup vs baseline: 1.1148x; 1.1148x over previous
//
#include <hip/hip_runtime.h>
#include <hip/hip_bf16.h>

// BinaryLinear: out = x @ sign(W)^T
// x: [32,4096,1024] f32 -> A [M=131072][K=1024]
// W: [1024,1024] f32    -> B^T = sign(W) [N=1024][K=1024] bf16 in d_ws (once)
// out: [M][N] f32
//
// R13: A LEAVES LDS ENTIRELY. The MFMA A-fragment (row=l&15, k-octet=l>>4 --
// same formula R6's LDS reads verified) is loaded straight from X with
// 2x global_load_dwordx4 (16 rows x 32B contiguous), cvt_pk'd in regs.
// Wave grid 4x1 (tile 32x128, acc[2][8]): A read ONCE per block; the 8
// N-sharers re-read it from the co-XCD L2 (swizzle). LDS holds only B
// (16 KB, R6-verbatim gll+XOR at BK=64). Sync = R6 verbatim: the A-load
// latency folds into the SAME per-step vmcnt(0) drain that already existed.
// LDS traffic/step 144->48 KB (pole ~135us); reg-staging arc (R8-R12) closed.

typedef __attribute__((ext_vector_type(8))) short bf16x8;
typedef __attribute__((ext_vector_type(4))) float f32x4;

#define BM 128
#define BN 128
#define BK 64
#define KDIM 1024
#define NDIM 1024
#define NKSTEP (KDIM / BK)

__device__ __forceinline__ unsigned cvt2(float a, float b) {
  unsigned r;
  asm("v_cvt_pk_bf16_f32 %0, %1, %2" : "=v"(r) : "v"(a), "v"(b));
  return r;
}

// ---- pre-kernel: Bs[n][k] = sign(W[n][k]) as bf16 (+1, -1, or 0) ----
__global__ void sign_kernel(const float4* __restrict__ W, ushort4* __restrict__ Bs, int n4) {
  int i = blockIdx.x * blockDim.x + threadIdx.x;
  if (i >= n4) return;
  float4 v = W[i];
  const float* pv = (const float*)&v;
  ushort4 r;
  unsigned short* pr = (unsigned short*)&r;
#pragma unroll
  for (int j = 0; j < 4; ++j) {
    union { float f; unsigned int u; } c; c.f = pv[j];
    pr[j] = ((c.u & 0x7fffffffu) == 0u)
                ? (unsigned short)0
                : (unsigned short)(0x3f80u | ((c.u >> 16) & 0x8000u));
  }
  Bs[i] = r;
}

// ---- main GEMM ----
__global__ __launch_bounds__(256) void bgemm_kernel(
    const float* __restrict__ X,
    const unsigned short* __restrict__ Bs,
    float* __restrict__ O) {
  // B only: 128 rows x 64 bf16, chunk-XOR slot layout (R6 verbatim) = 16 KB
  __shared__ unsigned short sB[BN * BK];

  const int t = threadIdx.x;
  const int l = t & 63;
  const int w = t >> 6;  // 4x1 wave grid: wave w owns rows w*32..w*32+31, all 128 cols

  // XCD-bijective swizzle; bn fastest => 8 N-sharers of an M-tile on one XCD.
  const unsigned nwg = gridDim.x;
  unsigned swz = blockIdx.x;
  if ((nwg & 7u) == 0u) swz = (blockIdx.x & 7u) * (nwg >> 3) + (blockIdx.x >> 3);
  const int bm = (int)(swz >> 3);
  const int bn = (int)(swz & 7u);
  const size_t m0 = (size_t)bm * BM;
  const int N0 = bn * BN;

  const int ll = l & 15;
  const int kb = l >> 4;

  // A direct-from-global fragment pointers: frag i covers rows w*32+i*16+ll,
  // k-octet kb; per step/ks the lane reads 8 consecutive f32 (32B) there.
  const float* aglp[2];
#pragma unroll
  for (int i = 0; i < 2; ++i)
    aglp[i] = X + (m0 + (size_t)(w * 32 + i * 16 + ll)) * KDIM + kb * 8;

  // B staging: 128x64 bf16 = 1024 16B-chunks, 4 gll/thread (R6 verbatim).
  // LDS chunk c = n*8 + s holds global k-octet q = s ^ (n&7).
  const unsigned short* bgp[4];
  int bw[4];
#pragma unroll
  for (int i = 0; i < 4; ++i) {
    int c = i * 256 + t;
    int n = c >> 3;
    int q = (c & 7) ^ (n & 7);
    bgp[i] = Bs + (size_t)(N0 + n) * KDIM + q * 8;
    bw[i] = c * 8;  // linear dest (gll rule)
  }

  // B fragment read offsets: 8 col-frags x 2 k-subs
  int offB[2][8];
#pragma unroll
  for (int ks = 0; ks < 2; ++ks)
#pragma unroll
    for (int j = 0; j < 8; ++j) {
      int n = j * 16 + ll;
      offB[ks][j] = n * BK + (((ks * 4 + kb) ^ (n & 7)) * 8);
    }

  f32x4 acc[2][8];
#pragma unroll
  for (int i = 0; i < 2; ++i)
#pragma unroll
    for (int j = 0; j < 8; ++j) acc[i][j] = (f32x4)0.0f;

  for (int kk = 0; kk < NKSTEP; ++kk) {
    const int k0 = kk * BK;

    // ---- stage phase ----
    // B -> LDS via gll (front of the queue)
#pragma unroll
    for (int i = 0; i < 4; ++i)
      __builtin_amdgcn_global_load_lds(
          (const __attribute__((address_space(1))) void*)(bgp[i] + k0),
          (__attribute__((address_space(3))) void*)(&sB[bw[i]]), 16, 0, 0);
    // A fragments -> regs: 2 frags x 2 ks x 2 dwordx4 = 8 loads, all issued now
    f32x4 alo[2][2], ahi[2][2];
#pragma unroll
    for (int ks = 0; ks < 2; ++ks)
#pragma unroll
      for (int i = 0; i < 2; ++i) {
        const float* p = aglp[i] + k0 + ks * 32;
        alo[ks][i] = *reinterpret_cast<const f32x4*>(p);
        ahi[ks][i] = *reinterpret_cast<const f32x4*>(p + 4);
      }
    // one drain covers B-gll AND the A register loads (same counter)
    asm volatile("s_waitcnt vmcnt(0) lgkmcnt(0)" ::: "memory");
    __syncthreads();

    // ---- compute: 2 k-subs x (2x8) MFMA ----
#pragma unroll
    for (int ks = 0; ks < 2; ++ks) {
      bf16x8 av[2];
#pragma unroll
      for (int i = 0; i < 2; ++i) {
        union { uint4 u; bf16x8 v; } cv;
        cv.u.x = cvt2(alo[ks][i].x, alo[ks][i].y);
        cv.u.y = cvt2(alo[ks][i].z, alo[ks][i].w);
        cv.u.z = cvt2(ahi[ks][i].x, ahi[ks][i].y);
        cv.u.w = cvt2(ahi[ks][i].z, ahi[ks][i].w);
        av[i] = cv.v;
      }
      bf16x8 bv[8];
#pragma unroll
      for (int j = 0; j < 8; ++j)
        bv[j] = *reinterpret_cast<const bf16x8*>(sB + offB[ks][j]);
#pragma unroll
      for (int i = 0; i < 2; ++i)
#pragma unroll
        for (int j = 0; j < 8; ++j)
          acc[i][j] = __builtin_amdgcn_mfma_f32_16x16x32_bf16(
              av[i], bv[j], acc[i][j], 0, 0, 0);
    }
    __syncthreads();  // B reads done before next step's stage overwrites
  }

  // epilogue: C/D layout col = lane&15, row = (lane>>4)*4 + reg
  const int crow = kb * 4;
#pragma unroll
  for (int i = 0; i < 2; ++i) {
    const size_t r0 = m0 + w * 32 + i * 16 + crow;
#pragma unroll
    for (int j = 0; j < 8; ++j) {
      const int col = N0 + j * 16 + ll;
      float* op = O + r0 * NDIM + col;
#pragma unroll
      for (int e = 0; e < 4; ++e) op[(size_t)e * NDIM] = acc[i][j][e];
    }
  }
}

// ---- fallback (only if ws too small for the 2 MiB sign buffer) ----
__global__ void naive_kernel(const float* __restrict__ X, const float* __restrict__ W,
                             float* __restrict__ O, long long total) {
  long long idx = (long long)blockIdx.x * blockDim.x + threadIdx.x;
  if (idx >= total) return;
  int n = (int)(idx & (NDIM - 1));
  long long m = idx >> 10;
  const float* xr = X + m * KDIM;
  const float* wr = W + (long long)n * KDIM;
  float s = 0.f;
  for (int k = 0; k < KDIM; ++k) {
    float wv = wr[k];
    float sg = (wv > 0.f) ? 1.f : ((wv < 0.f) ? -1.f : 0.f);
    s += xr[k] * sg;
  }
  O[idx] = s;
}

extern "C" void kernel_launch(void* const* d_in, const int* in_sizes, int n_in,
                              void* d_out, int out_size, void* d_ws, size_t ws_size,
                              hipStream_t stream) {
  const float* X = (const float*)d_in[0];
  const float* W = (const float*)d_in[1];
  float* O = (float*)d_out;
  const long long M = (long long)in_sizes[0] / KDIM;  // 131072

  const size_t need_ws = (size_t)NDIM * KDIM * sizeof(unsigned short);  // 2 MiB
  if (ws_size >= need_ws && (M % BM) == 0) {
    unsigned short* Bs = (unsigned short*)d_ws;
    int n4 = (NDIM * KDIM) / 4;
    sign_kernel<<<dim3(n4 / 256), dim3(256), 0, stream>>>(
        (const float4*)W, (ushort4*)Bs, n4);
    dim3 grid((unsigned)((M / BM) * (NDIM / BN)));  // 8192
    bgemm_kernel<<<grid, dim3(256), 0, stream>>>(X, Bs, O);
  } else {
    long long total = M * NDIM;
    long long blocks = (total + 255) / 256;
    naive_kernel<<<dim3((unsigned)blocks), dim3(256), 0, stream>>>(X, W, O, total);
  }
}

// Round 14
// 637.887 us; speedup vs baseline: 1.1585x; 1.0392x over previous
//
#include <hip/hip_runtime.h>
#include <hip/hip_bf16.h>

// BinaryLinear: out = x @ sign(W)^T
// x: [32,4096,1024] f32 -> A [M=131072][K=1024]
// W: [1024,1024] f32    -> B^T = sign(W) [N=1024][K=1024] bf16 in d_ws (once)
// out: [M][N] f32
//
// R14 = R6 (453us, the verified best; LDS-BW-bound at 1.25x its 362us pole)
// with a WIDER TILE to cut LDS traffic per FLOP, keeping R6's race-free
// structure verbatim (stage-gll -> vmcnt(0)+lgkm(0) -> barrier -> compute ->
// barrier, single buffer, all-gll staging, XOR layouts):
//   block 128x256, wave tile 64x128 (acc[4][8], R2's shape: VGPR 116, no
//   spill). Per-FLOP LDS traffic drops 1.5x (192KB per 4.2 MFLOP vs 144KB
//   per 2.1) -> pole 362->182us. LDS 64KB -> 2 blocks/CU.
// R7-R13 lesson: do NOT leave memory ops in flight during compute; do NOT
// pass a min-waves arg to launch_bounds (VGPR=64 trap).

typedef __attribute__((ext_vector_type(8))) short bf16x8;
typedef __attribute__((ext_vector_type(4))) float f32x4;

#define BM 128
#define BN 256
#define BK 64
#define KDIM 1024
#define NDIM 1024
#define NKSTEP (KDIM / BK)

__device__ __forceinline__ unsigned cvt2(float a, float b) {
  unsigned r;
  asm("v_cvt_pk_bf16_f32 %0, %1, %2" : "=v"(r) : "v"(a), "v"(b));
  return r;
}

// ---- pre-kernel: Bs[n][k] = sign(W[n][k]) as bf16 (+1, -1, or 0) ----
__global__ void sign_kernel(const float4* __restrict__ W, ushort4* __restrict__ Bs, int n4) {
  int i = blockIdx.x * blockDim.x + threadIdx.x;
  if (i >= n4) return;
  float4 v = W[i];
  const float* pv = (const float*)&v;
  ushort4 r;
  unsigned short* pr = (unsigned short*)&r;
#pragma unroll
  for (int j = 0; j < 4; ++j) {
    union { float f; unsigned int u; } c; c.f = pv[j];
    pr[j] = ((c.u & 0x7fffffffu) == 0u)
                ? (unsigned short)0
                : (unsigned short)(0x3f80u | ((c.u >> 16) & 0x8000u));
  }
  Bs[i] = r;
}

// ---- main GEMM ----
__global__ __launch_bounds__(256) void bgemm_kernel(
    const float* __restrict__ X,
    const unsigned short* __restrict__ Bs,
    float* __restrict__ O) {
  // A tile: 128 rows x 16 f32x4-chunks (16-slot XOR within row) = 32 KB
  // B tile: 256 rows x 8 16B-chunks  (8-slot XOR within row)    = 32 KB
  __shared__ f32x4 sA[BM * 16];
  __shared__ unsigned short sB[BN * BK];

  const int t = threadIdx.x;
  const int l = t & 63;
  const int w = t >> 6;
  const int wr = w >> 1;  // 2x2 wave grid, wave tile 64x128
  const int wc = w & 1;

  // XCD-bijective swizzle; bn fastest => 4 N-sharers of an M-tile on one XCD.
  const unsigned nwg = gridDim.x;  // 4096
  unsigned swz = blockIdx.x;
  if ((nwg & 7u) == 0u) swz = (blockIdx.x & 7u) * (nwg >> 3) + (blockIdx.x >> 3);
  const int bm = (int)(swz >> 2);
  const int bn = (int)(swz & 3u);
  const size_t m0 = (size_t)bm * BM;
  const int N0 = bn * BN;

  // A staging: 128x64 f32 = 2048 16B-chunks, 8 gll/thread (R6 verbatim).
  // LDS chunk c = r*16 + s holds global k-chunk q = s ^ (r&15).
  const float* agp[8];
#pragma unroll
  for (int i = 0; i < 8; ++i) {
    int c = i * 256 + t;
    int r = c >> 4;
    int q = (c & 15) ^ (r & 15);
    agp[i] = X + (m0 + (size_t)r) * KDIM + q * 4;
  }

  // B staging: 256x64 bf16 = 2048 16B-chunks, 8 gll/thread (R6 formula).
  // LDS chunk c = n*8 + s holds global k-octet q = s ^ (n&7).
  const unsigned short* bgp[8];
#pragma unroll
  for (int i = 0; i < 8; ++i) {
    int c = i * 256 + t;
    int n = c >> 3;
    int q = (c & 7) ^ (n & 7);
    bgp[i] = Bs + (size_t)(N0 + n) * KDIM + q * 8;
  }

  // fragment read offsets (2 k-subs of 32 per BK=64 step)
  const int ll = l & 15;
  const int kb = l >> 4;
  int idxA[2][4];  // f32x4-chunk index of low half; high = ^1
  int offB[2][8];  // ushort offset
#pragma unroll
  for (int ks = 0; ks < 2; ++ks) {
#pragma unroll
    for (int i = 0; i < 4; ++i) {
      int row = wr * 64 + i * 16 + ll;
      idxA[ks][i] = row * 16 + ((ks * 8 + kb * 2) ^ (row & 15));
    }
#pragma unroll
    for (int j = 0; j < 8; ++j) {
      int n = wc * 128 + j * 16 + ll;
      offB[ks][j] = n * BK + (((ks * 4 + kb) ^ (n & 7)) * 8);
    }
  }

  f32x4 acc[4][8];
#pragma unroll
  for (int i = 0; i < 4; ++i)
#pragma unroll
    for (int j = 0; j < 8; ++j) acc[i][j] = (f32x4)0.0f;

  for (int kk = 0; kk < NKSTEP; ++kk) {
    const int k0 = kk * BK;
    // ---- stage (single buffer, all-gll) ----
#pragma unroll
    for (int i = 0; i < 8; ++i)
      __builtin_amdgcn_global_load_lds(
          (const __attribute__((address_space(1))) void*)(agp[i] + k0),
          (__attribute__((address_space(3))) void*)(&sA[i * 256 + t]), 16, 0, 0);
#pragma unroll
    for (int i = 0; i < 8; ++i)
      __builtin_amdgcn_global_load_lds(
          (const __attribute__((address_space(1))) void*)(bgp[i] + k0),
          (__attribute__((address_space(3))) void*)(&sB[(i * 256 + t) * 8]), 16, 0, 0);
    // explicit drain before barrier (R6 discipline: race-free on replay)
    asm volatile("s_waitcnt vmcnt(0) lgkmcnt(0)" ::: "memory");
    __syncthreads();

    // ---- compute: 2 k-subs x (4x8) MFMA ----
#pragma unroll
    for (int ks = 0; ks < 2; ++ks) {
      bf16x8 av[4];
#pragma unroll
      for (int i = 0; i < 4; ++i) {
        f32x4 c0 = sA[idxA[ks][i]];
        f32x4 c1 = sA[idxA[ks][i] ^ 1];
        union { uint4 u; bf16x8 v; } cv;
        cv.u.x = cvt2(c0.x, c0.y); cv.u.y = cvt2(c0.z, c0.w);
        cv.u.z = cvt2(c1.x, c1.y); cv.u.w = cvt2(c1.z, c1.w);
        av[i] = cv.v;
      }
#pragma unroll
      for (int j = 0; j < 8; ++j) {
        bf16x8 bv = *reinterpret_cast<const bf16x8*>(sB + offB[ks][j]);
#pragma unroll
        for (int i = 0; i < 4; ++i)
          acc[i][j] = __builtin_amdgcn_mfma_f32_16x16x32_bf16(
              av[i], bv, acc[i][j], 0, 0, 0);
      }
    }
    __syncthreads();  // all reads done before next step's stage overwrites
  }

  // epilogue: C/D layout col = lane&15, row = (lane>>4)*4 + reg
  const int crow = kb * 4;
#pragma unroll
  for (int i = 0; i < 4; ++i) {
    const size_t r0 = m0 + wr * 64 + i * 16 + crow;
#pragma unroll
    for (int j = 0; j < 8; ++j) {
      const int col = N0 + wc * 128 + j * 16 + ll;
      float* op = O + r0 * NDIM + col;
#pragma unroll
      for (int e = 0; e < 4; ++e) op[(size_t)e * NDIM] = acc[i][j][e];
    }
  }
}

// ---- fallback (only if ws too small for the 2 MiB sign buffer) ----
__global__ void naive_kernel(const float* __restrict__ X, const float* __restrict__ W,
                             float* __restrict__ O, long long total) {
  long long idx = (long long)blockIdx.x * blockDim.x + threadIdx.x;
  if (idx >= total) return;
  int n = (int)(idx & (NDIM - 1));
  long long m = idx >> 10;
  const float* xr = X + m * KDIM;
  const float* wr = W + (long long)n * KDIM;
  float s = 0.f;
  for (int k = 0; k < KDIM; ++k) {
    float wv = wr[k];
    float sg = (wv > 0.f) ? 1.f : ((wv < 0.f) ? -1.f : 0.f);
    s += xr[k] * sg;
  }
  O[idx] = s;
}

extern "C" void kernel_launch(void* const* d_in, const int* in_sizes, int n_in,
                              void* d_out, int out_size, void* d_ws, size_t ws_size,
                              hipStream_t stream) {
  const float* X = (const float*)d_in[0];
  const float* W = (const float*)d_in[1];
  float* O = (float*)d_out;
  const long long M = (long long)in_sizes[0] / KDIM;  // 131072

  const size_t need_ws = (size_t)NDIM * KDIM * sizeof(unsigned short);  // 2 MiB
  if (ws_size >= need_ws && (M % BM) == 0) {
    unsigned short* Bs = (unsigned short*)d_ws;
    int n4 = (NDIM * KDIM) / 4;
    sign_kernel<<<dim3(n4 / 256), dim3(256), 0, stream>>>(
        (const float4*)W, (ushort4*)Bs, n4);
    dim3 grid((unsigned)((M / BM) * (NDIM / BN)));  // 4096
    bgemm_kernel<<<grid, dim3(256), 0, stream>>>(X, Bs, O);
  } else {
    long long total = M * NDIM;
    long long blocks = (total + 255) / 256;
    naive_kernel<<<dim3((unsigned)blocks), dim3(256), 0, stream>>>(X, W, O, total);
  }
}